// Round 5
// baseline (239.084 us; speedup 1.0000x reference)
//
#include <hip/hip_runtime.h>

// VQ-VAE vector quantizer, R22: R21 (16x16x32, 4 waves/SIMD) + 4-deep register
// prefetch + split accumulator chains.
// R21 post-mortem: occupancy goal hit (35%, VGPR=60, no spill) but 146us — per-group
// compute shrank to ~90cyc, so prefetch distance 1 issues loads only ~90cyc ahead of
// use vs ~200+cyc L2 latency (m126): every one of the 64 groups stalls. All pipes got
// LESS busy (Mfma 6.9, VALU 12). Latency must be covered by pipeline depth, not waves.
// Fix: 4 named B-buffers, prefetch distance 3 (~350cyc ahead); accumulator split into
// two 3-deep MFMA chains (halves the serial-latency path per group). ~+40 VGPR, still
// <=128 -> 4 waves/SIMD spill-free under __launch_bounds__(256,4).
// Wave = 16 points x 1024 codes (64 groups of 16). Block = 64 pts, grid = 1024.
// C layout (m89/m91): col=lane&15 (code), row=(lane>>4)*4+reg (point).
// Exactness: streaming top-2, strict-< lowest-idx tie-break, near-ties (<1e-3)
// rescanned exactly in fp32.
// out (fp32 concat): [ loss(1) | quantized NCHW (4194304) | indices as float (65536) ]

#define DIMS   64
#define HW     4096
#define NPTS   65536
#define NCODES 1024
#define NPB    64
#define QOFF   1
#define IOFF   (1 + NPTS * DIMS)
#define EPSGAP 1.0e-3f

typedef unsigned int uint;
typedef unsigned short ushort;
typedef unsigned long long ull;
typedef __attribute__((ext_vector_type(8))) short short8;
typedef __attribute__((ext_vector_type(4))) float f32x4;

__device__ __forceinline__ ushort bf16_rne(float f) {
    uint u = __float_as_uint(f);
    uint r = u + 0x7FFFu + ((u >> 16) & 1u);
    return (ushort)(r >> 16);
}
__device__ __forceinline__ float bf16f(ushort h) { return __uint_as_float(((uint)h) << 16); }

// ---- prep: emb fp32 -> {Eh, El bf16 [1024][64]}, hsq = 0.5||e||^2 (shuffle), zero out[0]
__global__ void vq_prep(const float* __restrict__ emb, ushort* __restrict__ Eh,
                        ushort* __restrict__ El, float* __restrict__ hsq,
                        float* __restrict__ out)
{
    const int t = blockIdx.x * 256 + threadIdx.x;      // 0..16383 = code*16 + dim-group
    if (t == 0) out[0] = 0.f;
    float4 v = ((const float4*)emb)[t];
    ushort h0 = bf16_rne(v.x), h1 = bf16_rne(v.y), h2 = bf16_rne(v.z), h3 = bf16_rne(v.w);
    ushort l0 = bf16_rne(v.x - bf16f(h0)), l1 = bf16_rne(v.y - bf16f(h1));
    ushort l2 = bf16_rne(v.z - bf16f(h2)), l3 = bf16_rne(v.w - bf16f(h3));
    uint2 hp, lp;
    hp.x = (uint)h0 | ((uint)h1 << 16); hp.y = (uint)h2 | ((uint)h3 << 16);
    lp.x = (uint)l0 | ((uint)l1 << 16); lp.y = (uint)l2 | ((uint)l3 << 16);
    *(uint2*)(Eh + (size_t)t * 4) = hp;
    *(uint2*)(El + (size_t)t * 4) = lp;
    // hsq: 16 consecutive lanes hold one code's 16 float4s -> xor-shuffle reduce
    float pe = fmaf(v.x, v.x, fmaf(v.y, v.y, fmaf(v.z, v.z, v.w * v.w)));
    pe += __shfl_xor(pe, 1); pe += __shfl_xor(pe, 2);
    pe += __shfl_xor(pe, 4); pe += __shfl_xor(pe, 8);
    if ((t & 15) == 0) hsq[t >> 4] = 0.5f * pe;
}

__launch_bounds__(256, 4)
__global__ void vq_main(const float* __restrict__ in, const float* __restrict__ emb,
                        const ushort* __restrict__ Ehw, const ushort* __restrict__ Elw,
                        const float* __restrict__ hsqw, float* __restrict__ out)
{
    __shared__ float sv1[NPB];
    __shared__ float sv2[NPB];
    __shared__ int   si1[NPB];
    __shared__ ull   msk;
    __shared__ int   lst[1 + NPB];
    __shared__ float lred[4];

    const int tid = threadIdx.x;
    const int lane = tid & 63, w = tid >> 6;
    const int m  = lane & 15;                          // point row (A) / code col (B)
    const int kq = lane >> 4;                          // k-quarter: k = kc*32 + kq*8 + j
    const int n0 = blockIdx.x * NPB;
    const int b = n0 >> 12, off = n0 & 4095;           // 64 | 4096: never crosses a batch
    const float* xbase = in + (size_t)b * (DIMS * HW) + off;

    // ---- A fragments: wave's 16 points, hi+lo bf16; two k-chunks of 32
    short8 Ah[2], Al[2];
    {
        const int p = w * 16 + m;
        #pragma unroll
        for (int kc = 0; kc < 2; ++kc) {
            union { ushort u[8]; short8 v; } th, tl;
            #pragma unroll
            for (int j = 0; j < 8; ++j) {
                float x = xbase[(kc * 32 + kq * 8 + j) * HW + p];
                ushort hh = bf16_rne(x);
                th.u[j] = hh;
                tl.u[j] = bf16_rne(x - bf16f(hh));
            }
            Ah[kc] = th.v; Al[kc] = tl.v;
        }
    }

    float v1s[4], v2s[4]; int i1s[4];
    #pragma unroll
    for (int r = 0; r < 4; ++r) { v1s[r] = 1e30f; v2s[r] = 1e30f; i1s[r] = 0; }

    auto loadB = [&](int g, short8 (&BH)[2], short8 (&BL)[2], float& HA) {
        const int ca = g * 16 + m;
        const ushort* eb = Ehw + (size_t)ca * 64 + kq * 8;
        const ushort* lb = Elw + (size_t)ca * 64 + kq * 8;
        #pragma unroll
        for (int kc = 0; kc < 2; ++kc) {
            BH[kc] = *(const short8*)(eb + kc * 32);
            BL[kc] = *(const short8*)(lb + kc * 32);
        }
        HA = hsqw[ca];
    };

    auto compute = [&](int g, const short8 (&BH)[2], const short8 (&BL)[2], float HA) {
        // two independent 3-deep chains (halve the serial MFMA latency path)
        f32x4 a1 = {0.f, 0.f, 0.f, 0.f};
        f32x4 a2 = {0.f, 0.f, 0.f, 0.f};
        a1 = __builtin_amdgcn_mfma_f32_16x16x32_bf16(Ah[0], BH[0], a1, 0, 0, 0);
        a2 = __builtin_amdgcn_mfma_f32_16x16x32_bf16(Ah[1], BL[1], a2, 0, 0, 0);
        a1 = __builtin_amdgcn_mfma_f32_16x16x32_bf16(Ah[1], BH[1], a1, 0, 0, 0);
        a2 = __builtin_amdgcn_mfma_f32_16x16x32_bf16(Al[0], BH[0], a2, 0, 0, 0);
        a1 = __builtin_amdgcn_mfma_f32_16x16x32_bf16(Ah[0], BL[0], a1, 0, 0, 0);
        a2 = __builtin_amdgcn_mfma_f32_16x16x32_bf16(Al[1], BH[1], a2, 0, 0, 0);
        const int ca = g * 16 + m;                     // this lane's code col
        #pragma unroll
        for (int r = 0; r < 4; ++r) {                  // r -> point row (fixed lane->code)
            float d = HA - (a1[r] + a2[r]);
            v2s[r] = fminf(v2s[r], fmaxf(d, v1s[r]));  // exact streaming 2nd-min
            bool c2 = d < v1s[r];                      // strict: ascending g keeps lowest idx
            i1s[r] = c2 ? ca : i1s[r];
            v1s[r] = fminf(d, v1s[r]);
        }
    };

    // ---- K-loop: 64 groups of 16 codes, 4-buffer register pipeline (distance 3)
    short8 B0h[2], B0l[2], B1h[2], B1l[2], B2h[2], B2l[2], B3h[2], B3l[2];
    float ha0, ha1, ha2, ha3;
    loadB(0, B0h, B0l, ha0);
    loadB(1, B1h, B1l, ha1);
    loadB(2, B2h, B2l, ha2);
    for (int g = 0; g < 64; g += 4) {
        loadB(g + 3, B3h, B3l, ha3);                   // ~3 computes ahead of use
        compute(g, B0h, B0l, ha0);
        if (g + 4 < 64) loadB(g + 4, B0h, B0l, ha0);
        compute(g + 1, B1h, B1l, ha1);
        if (g + 5 < 64) loadB(g + 5, B1h, B1l, ha1);
        compute(g + 2, B2h, B2l, ha2);
        if (g + 6 < 64) loadB(g + 6, B2h, B2l, ha2);
        compute(g + 3, B3h, B3l, ha3);
    }

    // ---- merge across the 16 code-lanes (each kq group holds 4 distinct point rows)
    #pragma unroll
    for (int st = 1; st < 16; st <<= 1) {
        #pragma unroll
        for (int r = 0; r < 4; ++r) {
            float ov1 = __shfl_xor(v1s[r], st);
            float ov2 = __shfl_xor(v2s[r], st);
            int   oi1 = __shfl_xor(i1s[r], st);
            v2s[r] = fminf(fminf(v2s[r], ov2), fmaxf(v1s[r], ov1));
            bool c = (ov1 < v1s[r]) || (ov1 == v1s[r] && oi1 < i1s[r]);
            if (c) i1s[r] = oi1;
            v1s[r] = fminf(v1s[r], ov1);
        }
    }
    if (m == 0) {                                      // lanes 0,16,32,48: 4 rows each
        #pragma unroll
        for (int r = 0; r < 4; ++r) {
            const int p = w * 16 + kq * 4 + r;         // C row = kq*4 + r
            sv1[p] = v1s[r]; si1[p] = i1s[r]; sv2[p] = v2s[r];
        }
    }
    __syncthreads();

    // ---- flag near-ties (wave 0, 64 lanes = 64 points)
    if (w == 0) {
        bool f = (sv2[lane] - sv1[lane]) < EPSGAP;
        ull bm = __ballot(f);
        if (lane == 0) msk = bm;
    }
    __syncthreads();
    if (tid == 0) {
        int c = 0;
        ull m0 = msk;
        while (m0) { lst[1 + c++] = __ffsll(m0) - 1; m0 &= m0 - 1; }
        lst[0] = c;
    }
    __syncthreads();

    // ---- exact fp32 rescan, one wave per flagged point (rare: gap < 1e-3)
    const int cnt = lst[0];
    const float4* e4 = (const float4*)emb;
    for (int it = w; it < cnt; it += 4) {
        const int p = lst[1 + it];
        float xv = xbase[lane * HW + p];               // lane d holds x_d (exact fp32)
        float bv = 1e30f; int bk = 0;
        #pragma unroll
        for (int half = 0; half < 2; ++half) {
            float dacc[8];
            #pragma unroll
            for (int j = 0; j < 8; ++j) dacc[j] = 0.f;
            for (int d4 = 0; d4 < 16; ++d4) {
                float x0 = __shfl(xv, d4 * 4 + 0), x1 = __shfl(xv, d4 * 4 + 1);
                float x2 = __shfl(xv, d4 * 4 + 2), x3 = __shfl(xv, d4 * 4 + 3);
                #pragma unroll
                for (int j = 0; j < 8; ++j) {
                    const int k = lane + 64 * (half * 8 + j);
                    float4 e = e4[k * 16 + d4];
                    dacc[j] = fmaf(x0, e.x, dacc[j]); dacc[j] = fmaf(x1, e.y, dacc[j]);
                    dacc[j] = fmaf(x2, e.z, dacc[j]); dacc[j] = fmaf(x3, e.w, dacc[j]);
                }
            }
            #pragma unroll
            for (int j = 0; j < 8; ++j) {              // ascending k per lane: first-min kept
                const int k = lane + 64 * (half * 8 + j);
                float v = hsqw[k] - dacc[j];
                if (v < bv) { bv = v; bk = k; }
            }
        }
        #pragma unroll
        for (int st = 32; st; st >>= 1) {              // 64-wide (v, k) argmin, k tie-break
            float ov = __shfl_xor(bv, st);
            int   ok = __shfl_xor(bk, st);
            if (ov < bv || (ov == bv && ok < bk)) { bv = ov; bk = ok; }
        }
        if (lane == 0) si1[p] = bk;
    }
    __syncthreads();

    // ---- final: indices, quantized gather-write, loss — 256 threads, 16 dims each
    {
        const int p = tid & 63, dg = tid >> 6;
        const int bi = si1[p];
        if (dg == 0) out[IOFF + n0 + p] = (float)bi;
        const float* e = emb + (size_t)bi * DIMS;
        const float* xp = xbase + p;
        float* oq = out + QOFF + (size_t)b * (DIMS * HW) + off + p;
        float ls = 0.f;
        #pragma unroll
        for (int d0 = 0; d0 < 16; ++d0) {
            const int d = dg * 16 + d0;
            float ev = e[d];
            float xv = xp[d * HW];
            float df = ev - xv;
            ls = fmaf(df, df, ls);
            oq[d * HW] = ev;                           // coalesced across point-threads
        }
        #pragma unroll
        for (int st = 32; st; st >>= 1) ls += __shfl_down(ls, st);
        if (lane == 0) lred[w] = ls;
    }
    __syncthreads();
    if (tid == 0) {
        float s = lred[0] + lred[1] + lred[2] + lred[3];
        atomicAdd(out, s * (0.25f / (float)(NPTS * DIMS)));
    }
}

extern "C" void kernel_launch(void* const* d_in, const int* in_sizes, int n_in,
                              void* d_out, int out_size, void* d_ws, size_t ws_size,
                              hipStream_t stream) {
    const float* in  = (const float*)d_in[0];
    const float* emb = (const float*)d_in[1];
    float* out = (float*)d_out;
    ushort* Eh  = (ushort*)d_ws;                       // 131072 B
    ushort* El  = (ushort*)((char*)d_ws + 131072);     // 131072 B
    float*  hsq = (float*)((char*)d_ws + 262144);      // 4096 B
    (void)in_sizes; (void)n_in; (void)out_size; (void)ws_size;

    vq_prep<<<64, 256, 0, stream>>>(emb, Eh, El, hsq, out);   // also zeroes out[0]
    vq_main<<<NPTS / NPB, 256, 0, stream>>>(in, emb, Eh, El, hsq, out);
}

// Round 6
// 168.897 us; speedup vs baseline: 1.4156x; 1.4156x over previous
//
#include <hip/hip_runtime.h>

// VQ-VAE vector quantizer, R23: fat waves + split-K + register diet (no B dbuf).
// Five-round model: (1) wave supply — 32-pt full-K waves give only 2048 waves = 2/SIMD
// machine cap (R18 96.5us, occ 16.5%); (2) true reg total incl AGPR ~172 blocks 4096-wave
// variants too (R20 108us, occ 15.5%); (3) thin 16-pt waves fix both but expose L2 latency
// on 64 short groups (R21 146us) and 4-deep pipelines spill (R22 184us, WRITE 44MB).
// R23: split-K2 (4096 waves) + 32x32 fat compute + SINGLE-buffered B (-33 regs -> ~157
// total -> 3 waves/SIMD). launch_bounds(256,3) caps hoisting at 168, non-binding for the
// ~140-reg live set => no spill. Prior session: prefetch variants were neutral at 2/SIMD,
// so dbuf's marginal value is small; 3-way TLP covers the ~200cyc L2 load per group.
// Wave = 32 points x 512 codes (16 groups of 32). Block 64 pts / 4 waves, grid 1024.
// Exactness unchanged: streaming top-2, strict-< lowest-idx tie-break, LDS cross-half
// merge (v2 = min(v2a,v2b,max(v1a,v1b))), near-ties (<1e-3) rescanned exactly in fp32.
// out (fp32 concat): [ loss(1) | quantized NCHW (4194304) | indices as float (65536) ]

#define DIMS   64
#define HW     4096
#define NPTS   65536
#define NCODES 1024
#define NPB    64
#define QOFF   1
#define IOFF   (1 + NPTS * DIMS)
#define EPSGAP 1.0e-3f

typedef unsigned int uint;
typedef unsigned short ushort;
typedef unsigned long long ull;
typedef __attribute__((ext_vector_type(8))) short short8;
typedef __attribute__((ext_vector_type(16))) float f32x16;

__device__ __forceinline__ ushort bf16_rne(float f) {
    uint u = __float_as_uint(f);
    uint r = u + 0x7FFFu + ((u >> 16) & 1u);
    return (ushort)(r >> 16);
}
__device__ __forceinline__ float bf16f(ushort h) { return __uint_as_float(((uint)h) << 16); }

// ---- prep: emb fp32 -> {Eh, El bf16 [1024][64]}, hsq = 0.5||e||^2 (shuffle), zero out[0]
__global__ void vq_prep(const float* __restrict__ emb, ushort* __restrict__ Eh,
                        ushort* __restrict__ El, float* __restrict__ hsq,
                        float* __restrict__ out)
{
    const int t = blockIdx.x * 256 + threadIdx.x;      // 0..16383 = code*16 + dim-group
    if (t == 0) out[0] = 0.f;
    float4 v = ((const float4*)emb)[t];
    ushort h0 = bf16_rne(v.x), h1 = bf16_rne(v.y), h2 = bf16_rne(v.z), h3 = bf16_rne(v.w);
    ushort l0 = bf16_rne(v.x - bf16f(h0)), l1 = bf16_rne(v.y - bf16f(h1));
    ushort l2 = bf16_rne(v.z - bf16f(h2)), l3 = bf16_rne(v.w - bf16f(h3));
    uint2 hp, lp;
    hp.x = (uint)h0 | ((uint)h1 << 16); hp.y = (uint)h2 | ((uint)h3 << 16);
    lp.x = (uint)l0 | ((uint)l1 << 16); lp.y = (uint)l2 | ((uint)l3 << 16);
    *(uint2*)(Eh + (size_t)t * 4) = hp;
    *(uint2*)(El + (size_t)t * 4) = lp;
    // hsq: 16 consecutive lanes hold one code's 16 float4s -> xor-shuffle reduce
    float pe = fmaf(v.x, v.x, fmaf(v.y, v.y, fmaf(v.z, v.z, v.w * v.w)));
    pe += __shfl_xor(pe, 1); pe += __shfl_xor(pe, 2);
    pe += __shfl_xor(pe, 4); pe += __shfl_xor(pe, 8);
    if ((t & 15) == 0) hsq[t >> 4] = 0.5f * pe;
}

__launch_bounds__(256, 3)
__global__ void vq_main(const float* __restrict__ in, const float* __restrict__ emb,
                        const ushort* __restrict__ Ehw, const ushort* __restrict__ Elw,
                        const float* __restrict__ hsqw, float* __restrict__ out)
{
    __shared__ float sv1[2][NPB];
    __shared__ float sv2[2][NPB];
    __shared__ int   si1[2][NPB];
    __shared__ ull   msk;
    __shared__ int   lst[1 + NPB];
    __shared__ float lred[4];

    const int tid = threadIdx.x;
    const int lane = tid & 63, w = tid >> 6;
    const int nn = lane & 31;                          // row (A) / col (B) within 32
    const int h  = lane >> 5;                          // k-half selector (dot product)
    const int pgrp = w >> 1;                           // point group (0,1): 32 points each
    const int ch   = w & 1;                            // code half (0: 0..511, 1: 512..1023)
    const int n0 = blockIdx.x * NPB;
    const int b = n0 >> 12, off = n0 & 4095;           // 64 | 4096: never crosses a batch
    const float* xbase = in + (size_t)b * (DIMS * HW) + off;

    // ---- A fragments: wave's 32 points, hi+lo bf16; k = ks*16 + 8h + j
    short8 Ah[4], Al[4];
    {
        const int p = pgrp * 32 + nn;
        #pragma unroll
        for (int ks = 0; ks < 4; ++ks) {
            union { ushort u[8]; short8 v; } th, tl;
            #pragma unroll
            for (int j = 0; j < 8; ++j) {
                float x = xbase[(ks * 16 + h * 8 + j) * HW + p];
                ushort hh = bf16_rne(x);
                th.u[j] = hh;
                tl.u[j] = bf16_rne(x - bf16f(hh));
            }
            Ah[ks] = th.v; Al[ks] = tl.v;
        }
    }

    float v1s[16], v2s[16]; int i1s[16];
    #pragma unroll
    for (int r = 0; r < 16; ++r) { v1s[r] = 1e30f; v2s[r] = 1e30f; i1s[r] = 0; }

    auto loadB = [&](int g, short8 (&BH)[4], short8 (&BL)[4], float& HA) {
        const int ca = ch * 512 + g * 32 + nn;
        const ushort* eb = Ehw + (size_t)ca * 64 + h * 8;
        const ushort* lb = Elw + (size_t)ca * 64 + h * 8;
        #pragma unroll
        for (int ks = 0; ks < 4; ++ks) {
            BH[ks] = *(const short8*)(eb + ks * 16);
            BL[ks] = *(const short8*)(lb + ks * 16);
        }
        HA = hsqw[ca];
    };

    auto compute = [&](int g, const short8 (&BH)[4], const short8 (&BL)[4], float HA) {
        f32x16 a1 = {0.f,0.f,0.f,0.f,0.f,0.f,0.f,0.f,0.f,0.f,0.f,0.f,0.f,0.f,0.f,0.f};
        f32x16 a2 = {0.f,0.f,0.f,0.f,0.f,0.f,0.f,0.f,0.f,0.f,0.f,0.f,0.f,0.f,0.f,0.f};
        #pragma unroll
        for (int ks = 0; ks < 4; ++ks)                 // chain 1: hh (4-deep)
            a1 = __builtin_amdgcn_mfma_f32_32x32x16_bf16(Ah[ks], BH[ks], a1, 0, 0, 0);
        #pragma unroll
        for (int ks = 0; ks < 4; ++ks)                 // chain 2a: hl
            a2 = __builtin_amdgcn_mfma_f32_32x32x16_bf16(Ah[ks], BL[ks], a2, 0, 0, 0);
        #pragma unroll
        for (int ks = 0; ks < 4; ++ks)                 // chain 2b: lh (same acc, 8-deep)
            a2 = __builtin_amdgcn_mfma_f32_32x32x16_bf16(Al[ks], BH[ks], a2, 0, 0, 0);
        const int ca = ch * 512 + g * 32 + nn;
        #pragma unroll
        for (int r = 0; r < 16; ++r) {                 // r -> point row (fixed lane->code)
            float d = HA - (a1[r] + a2[r]);
            v2s[r] = fminf(v2s[r], fmaxf(d, v1s[r]));  // exact streaming 2nd-min
            bool c2 = d < v1s[r];                      // strict: ascending g keeps lowest idx
            i1s[r] = c2 ? ca : i1s[r];
            v1s[r] = fminf(d, v1s[r]);
        }
    };

    // ---- K-loop: 16 groups of 32 codes (this wave's code half), single-buffered B
    {
        short8 Bh[4], Bl[4];
        float ha;
        for (int g = 0; g < 16; ++g) {
            loadB(g, Bh, Bl, ha);
            compute(g, Bh, Bl, ha);
        }
    }

    // ---- merge across the 32 code-lanes (both k-halves of a point share a half-wave)
    #pragma unroll
    for (int st = 1; st < 32; st <<= 1) {
        #pragma unroll
        for (int r = 0; r < 16; ++r) {
            float ov1 = __shfl_xor(v1s[r], st);
            float ov2 = __shfl_xor(v2s[r], st);
            int   oi1 = __shfl_xor(i1s[r], st);
            v2s[r] = fminf(fminf(v2s[r], ov2), fmaxf(v1s[r], ov1));
            bool c = (ov1 < v1s[r]) || (ov1 == v1s[r] && oi1 < i1s[r]);
            if (c) i1s[r] = oi1;
            v1s[r] = fminf(v1s[r], ov1);
        }
    }
    if (nn == 0) {                                     // lanes 0 and 32 hold 16 rows each
        #pragma unroll
        for (int r = 0; r < 16; ++r) {
            const int row = (r & 3) + 8 * (r >> 2) + 4 * h;
            const int p = pgrp * 32 + row;
            sv1[ch][p] = v1s[r]; si1[ch][p] = i1s[r]; sv2[ch][p] = v2s[r];
        }
    }
    __syncthreads();

    // ---- merge the two code halves (wave 0, 64 lanes = 64 points) + flag near-ties
    if (w == 0) {
        float a1v = sv1[0][lane], b1v = sv1[1][lane];
        float a2v = sv2[0][lane], b2v = sv2[1][lane];
        int   ai  = si1[0][lane], bi  = si1[1][lane];
        float m2 = fminf(fminf(a2v, b2v), fmaxf(a1v, b1v));
        if (b1v < a1v) { a1v = b1v; ai = bi; }         // half-1 idx all >=512: strict < ok
        sv1[0][lane] = a1v; si1[0][lane] = ai; sv2[0][lane] = m2;
        bool f = (m2 - a1v) < EPSGAP;
        ull bm = __ballot(f);
        if (lane == 0) msk = bm;
    }
    __syncthreads();
    if (tid == 0) {
        int c = 0;
        ull m0 = msk;
        while (m0) { lst[1 + c++] = __ffsll(m0) - 1; m0 &= m0 - 1; }
        lst[0] = c;
    }
    __syncthreads();

    // ---- exact fp32 rescan, one wave per flagged point (rare: gap < 1e-3)
    const int cnt = lst[0];
    const float4* e4 = (const float4*)emb;
    for (int it = w; it < cnt; it += 4) {
        const int p = lst[1 + it];
        float xv = xbase[lane * HW + p];               // lane d holds x_d (exact fp32)
        float bv = 1e30f; int bk = 0;
        #pragma unroll
        for (int half = 0; half < 2; ++half) {
            float dacc[8];
            #pragma unroll
            for (int j = 0; j < 8; ++j) dacc[j] = 0.f;
            for (int d4 = 0; d4 < 16; ++d4) {
                float x0 = __shfl(xv, d4 * 4 + 0), x1 = __shfl(xv, d4 * 4 + 1);
                float x2 = __shfl(xv, d4 * 4 + 2), x3 = __shfl(xv, d4 * 4 + 3);
                #pragma unroll
                for (int j = 0; j < 8; ++j) {
                    const int k = lane + 64 * (half * 8 + j);
                    float4 e = e4[k * 16 + d4];
                    dacc[j] = fmaf(x0, e.x, dacc[j]); dacc[j] = fmaf(x1, e.y, dacc[j]);
                    dacc[j] = fmaf(x2, e.z, dacc[j]); dacc[j] = fmaf(x3, e.w, dacc[j]);
                }
            }
            #pragma unroll
            for (int j = 0; j < 8; ++j) {              // ascending k per lane: first-min kept
                const int k = lane + 64 * (half * 8 + j);
                float v = hsqw[k] - dacc[j];
                if (v < bv) { bv = v; bk = k; }
            }
        }
        #pragma unroll
        for (int st = 32; st; st >>= 1) {              // 64-wide (v, k) argmin, k tie-break
            float ov = __shfl_xor(bv, st);
            int   ok = __shfl_xor(bk, st);
            if (ov < bv || (ov == bv && ok < bk)) { bv = ov; bk = ok; }
        }
        if (lane == 0) si1[0][p] = bk;
    }
    __syncthreads();

    // ---- final: indices, quantized gather-write, loss — 256 threads, 16 dims each
    {
        const int p = tid & 63, dg = tid >> 6;
        const int bi = si1[0][p];
        if (dg == 0) out[IOFF + n0 + p] = (float)bi;
        const float* e = emb + (size_t)bi * DIMS;
        const float* xp = xbase + p;
        float* oq = out + QOFF + (size_t)b * (DIMS * HW) + off + p;
        float ls = 0.f;
        #pragma unroll
        for (int d0 = 0; d0 < 16; ++d0) {
            const int d = dg * 16 + d0;
            float ev = e[d];
            float xv = xp[d * HW];
            float df = ev - xv;
            ls = fmaf(df, df, ls);
            oq[d * HW] = ev;                           // coalesced across point-threads
        }
        #pragma unroll
        for (int st = 32; st; st >>= 1) ls += __shfl_down(ls, st);
        if (lane == 0) lred[w] = ls;
    }
    __syncthreads();
    if (tid == 0) {
        float s = lred[0] + lred[1] + lred[2] + lred[3];
        atomicAdd(out, s * (0.25f / (float)(NPTS * DIMS)));
    }
}

extern "C" void kernel_launch(void* const* d_in, const int* in_sizes, int n_in,
                              void* d_out, int out_size, void* d_ws, size_t ws_size,
                              hipStream_t stream) {
    const float* in  = (const float*)d_in[0];
    const float* emb = (const float*)d_in[1];
    float* out = (float*)d_out;
    ushort* Eh  = (ushort*)d_ws;                       // 131072 B
    ushort* El  = (ushort*)((char*)d_ws + 131072);     // 131072 B
    float*  hsq = (float*)((char*)d_ws + 262144);      // 4096 B
    (void)in_sizes; (void)n_in; (void)out_size; (void)ws_size;

    vq_prep<<<64, 256, 0, stream>>>(emb, Eh, El, hsq, out);   // also zeroes out[0]
    vq_main<<<NPTS / NPB, 256, 0, stream>>>(in, emb, Eh, El, hsq, out);
}

// Round 7
// 123.837 us; speedup vs baseline: 1.9306x; 1.3639x over previous
//
#include <hip/hip_runtime.h>

// VQ-VAE vector quantizer, R24: R18 geometry + async LDS B-staging with counted vmcnt.
// Six-round model: occupancy is NOT the lever (R19-R23: every occupancy gain lost more
// in pipeline quality; R18 fat-wave+prefetch 96.5us stands). Regime = exposed VMEM
// latency per K-group. Fix: B leaves the VMEM path. All 4 waves share B -> stage
// Eh/El per-group tiles into LDS via global_load_lds(16B) into an 8-buffer ring,
// prefetch distance 3 (depth lives in LDS, zero VGPR cost), COUNTED s_waitcnt vmcnt(6)
// + raw s_barrier per group (a __syncthreads drain would reproduce R23's stall).
// Tables are pre-tiled by prep into MFMA-fragment order: lane l reads its B fragment
// at [ks*1024 + l*16] -> staging is a linear copy AND ds_read_b128 is conflict-free.
// Per-wave B-loads: 9 L2 gathers/group -> 2 async stages + 4+4 lane-linear ds_reads.
// hsq rides the same pipeline in named rotating registers (3 VMEM/iter/wave exact).
// Math bit-identical to R18: 32x32x16 MFMA, dot = xh.eh + xh.el + xl.eh, exact
// streaming top-2, strict-< lowest-idx, near-ties (<1e-3) rescanned exactly in fp32.
// out (fp32 concat): [ loss(1) | quantized NCHW (4194304) | indices as float (65536) ]

#define DIMS   64
#define HW     4096
#define NPTS   65536
#define NCODES 1024
#define NPB    128
#define QOFF   1
#define IOFF   (1 + NPTS * DIMS)
#define EPSGAP 1.0e-3f

typedef unsigned int uint;
typedef unsigned short ushort;
typedef unsigned long long ull;
typedef __attribute__((ext_vector_type(8))) short short8;
typedef __attribute__((ext_vector_type(16))) float f32x16;

__device__ __forceinline__ ushort bf16_rne(float f) {
    uint u = __float_as_uint(f);
    uint r = u + 0x7FFFu + ((u >> 16) & 1u);
    return (ushort)(r >> 16);
}
__device__ __forceinline__ float bf16f(ushort h) { return __uint_as_float(((uint)h) << 16); }

__device__ __forceinline__ void gload16(const void* g, void* l) {
    __builtin_amdgcn_global_load_lds(
        (const __attribute__((address_space(1))) void*)g,
        (__attribute__((address_space(3))) void*)l, 16, 0, 0);
}

// ---- prep: emb fp32 -> tiled {Eh, El} in MFMA-fragment order + hsq = 0.5||e||^2.
// Element (code c, dim d) -> ushort index g*2048 + ks*512 + (hh*32 + (c&31))*8 + (d&7),
// where g=c>>5, ks=d>>4, hh=(d>>3)&1. Lane l of group g then reads its fragment at
// [g][ks*512 + l*8] — linear in lane, so global_load_lds staging needs no swizzle.
__global__ void vq_prep(const float* __restrict__ emb, ushort* __restrict__ Eh,
                        ushort* __restrict__ El, float* __restrict__ hsq,
                        float* __restrict__ out)
{
    const int t = blockIdx.x * 256 + threadIdx.x;      // 0..16383 = code*16 + dim-group
    if (t == 0) out[0] = 0.f;
    float4 v = ((const float4*)emb)[t];
    ushort h0 = bf16_rne(v.x), h1 = bf16_rne(v.y), h2 = bf16_rne(v.z), h3 = bf16_rne(v.w);
    ushort l0 = bf16_rne(v.x - bf16f(h0)), l1 = bf16_rne(v.y - bf16f(h1));
    ushort l2 = bf16_rne(v.z - bf16f(h2)), l3 = bf16_rne(v.w - bf16f(h3));
    uint2 hp, lp;
    hp.x = (uint)h0 | ((uint)h1 << 16); hp.y = (uint)h2 | ((uint)h3 << 16);
    lp.x = (uint)l0 | ((uint)l1 << 16); lp.y = (uint)l2 | ((uint)l3 << 16);
    const int c = t >> 4, q = t & 15;
    const int g = c >> 5, nn = c & 31;
    const int d0 = q * 4;
    const int ks = d0 >> 4, hh = (d0 >> 3) & 1, j0 = d0 & 7;   // j0 in {0,4}
    const int base = g * 2048 + ks * 512 + (hh * 32 + nn) * 8 + j0;
    *(uint2*)(Eh + base) = hp;
    *(uint2*)(El + base) = lp;
    // hsq: 16 consecutive lanes hold one code's 16 float4s -> xor-shuffle reduce
    float pe = fmaf(v.x, v.x, fmaf(v.y, v.y, fmaf(v.z, v.z, v.w * v.w)));
    pe += __shfl_xor(pe, 1); pe += __shfl_xor(pe, 2);
    pe += __shfl_xor(pe, 4); pe += __shfl_xor(pe, 8);
    if ((t & 15) == 0) hsq[t >> 4] = 0.5f * pe;
}

__launch_bounds__(256, 2)
__global__ void vq_main(const float* __restrict__ in, const float* __restrict__ emb,
                        const ushort* __restrict__ Ehw, const ushort* __restrict__ Elw,
                        const float* __restrict__ hsqw, float* __restrict__ out)
{
    __shared__ ushort sEh[8][2048];                    // 8-buffer ring, 4KB per buffer
    __shared__ ushort sEl[8][2048];
    __shared__ float sv1[NPB];
    __shared__ float sv2[NPB];
    __shared__ int   si1[NPB];
    __shared__ ull   msk[2];
    __shared__ int   lst[1 + NPB];
    __shared__ float lred[4];

    const int tid = threadIdx.x;
    const int lane = tid & 63, w = tid >> 6;
    const int nn = lane & 31;                          // row (A) / col (B) within 32
    const int h  = lane >> 5;                          // k-half selector
    const int n0 = blockIdx.x * NPB;
    const int b = n0 >> 12, off = n0 & 4095;           // 128 | 4096: never crosses a batch
    const float* xbase = in + (size_t)b * (DIMS * HW) + off;

    // ---- A fragments: wave's 32 points, hi+lo bf16; k = ks*16 + 8h + j
    short8 Ah[4], Al[4];
    {
        const int p = w * 32 + nn;
        #pragma unroll
        for (int ks = 0; ks < 4; ++ks) {
            union { ushort u[8]; short8 v; } th, tl;
            #pragma unroll
            for (int j = 0; j < 8; ++j) {
                float x = xbase[(ks * 16 + h * 8 + j) * HW + p];
                ushort hh = bf16_rne(x);
                th.u[j] = hh;
                tl.u[j] = bf16_rne(x - bf16f(hh));
            }
            Ah[ks] = th.v; Al[ks] = tl.v;
        }
    }
    __builtin_amdgcn_sched_barrier(0);                 // keep A-loads out of counted region

    float v1s[16], v2s[16]; int i1s[16];
    #pragma unroll
    for (int r = 0; r < 16; ++r) { v1s[r] = 1e30f; v2s[r] = 1e30f; i1s[r] = 0; }

    // wave w stages chunks {2w, 2w+1} of the group's 8KB (i<4 -> Eh, else El): exactly
    // 2 global_load_lds per wave per group — the vmcnt(6) count relies on this.
    auto stage = [&](int sg, int buf) {
        #pragma unroll
        for (int u = 0; u < 2; ++u) {
            const int i = 2 * w + u;
            const int c4 = (i & 3) * 512;
            if (i < 4) gload16(Ehw + (size_t)sg * 2048 + c4 + lane * 8, &sEh[buf][c4]);
            else       gload16(Elw + (size_t)sg * 2048 + c4 + lane * 8, &sEl[buf][c4]);
        }
    };

    auto computeG = [&](int g, int buf, float HA) {
        short8 Bh[4], Bl[4];
        #pragma unroll
        for (int ks = 0; ks < 4; ++ks) {               // lane-linear ds_read_b128 x8
            Bh[ks] = *(const short8*)&sEh[buf][ks * 512 + lane * 8];
            Bl[ks] = *(const short8*)&sEl[buf][ks * 512 + lane * 8];
        }
        f32x16 a1 = {0.f,0.f,0.f,0.f,0.f,0.f,0.f,0.f,0.f,0.f,0.f,0.f,0.f,0.f,0.f,0.f};
        f32x16 a2 = {0.f,0.f,0.f,0.f,0.f,0.f,0.f,0.f,0.f,0.f,0.f,0.f,0.f,0.f,0.f,0.f};
        #pragma unroll
        for (int ks = 0; ks < 4; ++ks)                 // chain 1: hh (4-deep)
            a1 = __builtin_amdgcn_mfma_f32_32x32x16_bf16(Ah[ks], Bh[ks], a1, 0, 0, 0);
        #pragma unroll
        for (int ks = 0; ks < 4; ++ks)                 // chain 2a: hl
            a2 = __builtin_amdgcn_mfma_f32_32x32x16_bf16(Ah[ks], Bl[ks], a2, 0, 0, 0);
        #pragma unroll
        for (int ks = 0; ks < 4; ++ks)                 // chain 2b: lh (same acc, 8-deep)
            a2 = __builtin_amdgcn_mfma_f32_32x32x16_bf16(Al[ks], Bh[ks], a2, 0, 0, 0);
        const int ca = g * 32 + nn;
        #pragma unroll
        for (int r = 0; r < 16; ++r) {                 // r -> point row (fixed lane->code)
            float d = HA - (a1[r] + a2[r]);
            v2s[r] = fminf(v2s[r], fmaxf(d, v1s[r]));  // exact streaming 2nd-min
            bool c2 = d < v1s[r];                      // strict: ascending g keeps lowest idx
            i1s[r] = c2 ? ca : i1s[r];
            v1s[r] = fminf(d, v1s[r]);
        }
    };

    // ---- K-loop: 32 groups of 32 codes; LDS ring-8, prefetch distance 3.
    // Per iter/wave: 2 stages + 1 hsq = 3 VMEM (tail dummy-clamped to keep count exact).
    // vmcnt(6) + raw s_barrier in ONE asm: group-g data complete, no full drain.
    stage(0, 0); float hqA = hsqw[nn];
    stage(1, 1); float hqB = hsqw[32 + nn];
    stage(2, 2); float hqC = hsqw[64 + nn];
    float hqD;
    #pragma unroll 1
    for (int g = 0; g < 32; g += 4) {
        {
            const int s = g + 3;                       // <=31 always
            stage(s, (g + 3) & 7); hqD = hsqw[s * 32 + nn];
            asm volatile("s_waitcnt vmcnt(6)\ns_barrier" ::: "memory");
            computeG(g, g & 7, hqA);
        }
        {
            const int s = (g + 4 < 32) ? g + 4 : 31;
            stage(s, (g + 4) & 7); hqA = hsqw[s * 32 + nn];
            asm volatile("s_waitcnt vmcnt(6)\ns_barrier" ::: "memory");
            computeG(g + 1, (g + 1) & 7, hqB);
        }
        {
            const int s = (g + 5 < 32) ? g + 5 : 31;
            stage(s, (g + 5) & 7); hqB = hsqw[s * 32 + nn];
            asm volatile("s_waitcnt vmcnt(6)\ns_barrier" ::: "memory");
            computeG(g + 2, (g + 2) & 7, hqC);
        }
        {
            const int s = (g + 6 < 32) ? g + 6 : 31;
            stage(s, (g + 6) & 7); hqC = hsqw[s * 32 + nn];
            asm volatile("s_waitcnt vmcnt(6)\ns_barrier" ::: "memory");
            computeG(g + 3, (g + 3) & 7, hqD);
        }
    }

    // ---- merge across the 32 code-lanes (both k-halves of a point share a half-wave)
    #pragma unroll
    for (int st = 1; st < 32; st <<= 1) {
        #pragma unroll
        for (int r = 0; r < 16; ++r) {
            float ov1 = __shfl_xor(v1s[r], st);
            float ov2 = __shfl_xor(v2s[r], st);
            int   oi1 = __shfl_xor(i1s[r], st);
            v2s[r] = fminf(fminf(v2s[r], ov2), fmaxf(v1s[r], ov1));
            bool c = (ov1 < v1s[r]) || (ov1 == v1s[r] && oi1 < i1s[r]);
            if (c) i1s[r] = oi1;
            v1s[r] = fminf(v1s[r], ov1);
        }
    }
    if (nn == 0) {                                     // lanes 0 and 32 hold 16 rows each
        #pragma unroll
        for (int r = 0; r < 16; ++r) {
            const int row = (r & 3) + 8 * (r >> 2) + 4 * h;
            const int p = w * 32 + row;
            sv1[p] = v1s[r]; si1[p] = i1s[r]; sv2[p] = v2s[r];
        }
    }
    __syncthreads();

    // ---- flag near-ties (waves 0,1 cover points 0..127)
    {
        bool f = (tid < NPB) && ((sv2[tid] - sv1[tid]) < EPSGAP);
        ull bm = __ballot(f);
        if (lane == 0 && w < 2) msk[w] = bm;
    }
    __syncthreads();
    if (tid == 0) {
        int c = 0;
        ull m0 = msk[0];
        while (m0) { lst[1 + c++] = __ffsll(m0) - 1; m0 &= m0 - 1; }
        ull m1 = msk[1];
        while (m1) { lst[1 + c++] = 64 + (__ffsll(m1) - 1); m1 &= m1 - 1; }
        lst[0] = c;
    }
    __syncthreads();

    // ---- exact fp32 rescan, one wave per flagged point (rare: gap < 1e-3)
    const int cnt = lst[0];
    const float4* e4 = (const float4*)emb;
    for (int it = w; it < cnt; it += 4) {
        const int p = lst[1 + it];
        float xv = xbase[lane * HW + p];               // lane d holds x_d (exact fp32)
        float bv = 1e30f; int bk = 0;
        #pragma unroll
        for (int half = 0; half < 2; ++half) {
            float dacc[8];
            #pragma unroll
            for (int j = 0; j < 8; ++j) dacc[j] = 0.f;
            for (int d4 = 0; d4 < 16; ++d4) {
                float x0 = __shfl(xv, d4 * 4 + 0), x1 = __shfl(xv, d4 * 4 + 1);
                float x2 = __shfl(xv, d4 * 4 + 2), x3 = __shfl(xv, d4 * 4 + 3);
                #pragma unroll
                for (int j = 0; j < 8; ++j) {
                    const int k = lane + 64 * (half * 8 + j);
                    float4 e = e4[k * 16 + d4];
                    dacc[j] = fmaf(x0, e.x, dacc[j]); dacc[j] = fmaf(x1, e.y, dacc[j]);
                    dacc[j] = fmaf(x2, e.z, dacc[j]); dacc[j] = fmaf(x3, e.w, dacc[j]);
                }
            }
            #pragma unroll
            for (int j = 0; j < 8; ++j) {              // ascending k per lane: first-min kept
                const int k = lane + 64 * (half * 8 + j);
                float v = hsqw[k] - dacc[j];
                if (v < bv) { bv = v; bk = k; }
            }
        }
        #pragma unroll
        for (int st = 32; st; st >>= 1) {              // 64-wide (v, k) argmin, k tie-break
            float ov = __shfl_xor(bv, st);
            int   ok = __shfl_xor(bk, st);
            if (ov < bv || (ov == bv && ok < bk)) { bv = ov; bk = ok; }
        }
        if (lane == 0) si1[p] = bk;
    }
    __syncthreads();

    // ---- final: indices, quantized gather-write, loss — all 256 threads (32 dims each)
    {
        const int p = tid & 127, dg = tid >> 7;
        const int bi = si1[p];
        if (dg == 0) out[IOFF + n0 + p] = (float)bi;
        const float* e = emb + (size_t)bi * DIMS;
        const float* xp = xbase + p;
        float* oq = out + QOFF + (size_t)b * (DIMS * HW) + off + p;
        float ls = 0.f;
        #pragma unroll
        for (int d0 = 0; d0 < 32; ++d0) {
            const int d = dg * 32 + d0;
            float ev = e[d];
            float xv = xp[d * HW];
            float df = ev - xv;
            ls = fmaf(df, df, ls);
            oq[d * HW] = ev;                           // coalesced across point-threads
        }
        #pragma unroll
        for (int st = 32; st; st >>= 1) ls += __shfl_down(ls, st);
        if (lane == 0) lred[w] = ls;
    }
    __syncthreads();
    if (tid == 0) {
        float s = lred[0] + lred[1] + lred[2] + lred[3];
        atomicAdd(out, s * (0.25f / (float)(NPTS * DIMS)));
    }
}

extern "C" void kernel_launch(void* const* d_in, const int* in_sizes, int n_in,
                              void* d_out, int out_size, void* d_ws, size_t ws_size,
                              hipStream_t stream) {
    const float* in  = (const float*)d_in[0];
    const float* emb = (const float*)d_in[1];
    float* out = (float*)d_out;
    ushort* Eh  = (ushort*)d_ws;                       // 131072 B (tiled fragment order)
    ushort* El  = (ushort*)((char*)d_ws + 131072);     // 131072 B
    float*  hsq = (float*)((char*)d_ws + 262144);      // 4096 B
    (void)in_sizes; (void)n_in; (void)out_size; (void)ws_size;

    vq_prep<<<64, 256, 0, stream>>>(emb, Eh, El, hsq, out);   // also zeroes out[0]
    vq_main<<<NPTS / NPB, 256, 0, stream>>>(in, emb, Eh, El, hsq, out);
}